// Round 4
// baseline (55.523 us; speedup 1.0000x reference)
//
#include <hip/hip_runtime.h>

// Word2vec SGNS loss: sum over B*(K+1)=344064 pairs of softplus(-dot64(u_row,v_row)).
// fp32 embeddings, 1e6 x 64 (256 B rows). Random gather, throughput-bound at the
// HBM random-256B rate (~88 MB fetch @ ~2.9 TB/s effective ≈ 30 us).
// Epilogue: one fire-and-forget atomicAdd per block (no-return global_atomic_add_f32
// pipelines; round-2 lesson: ACQ_REL fetch_add w/ return serializes ~60ns each).
// d_out zeroed via memset node each call -> deterministic across graph replays.

constexpr int Bn = 16384;
constexpr int Kn = 20;
constexpr int Dn = 64;
constexpr int NPAIRS = Bn * (Kn + 1);   // 344064

#define BDIM 256
#define NBLOCKS 2048
#define NGROUPS ((NBLOCKS * BDIM) >> 4)   // 32768 16-lane groups

__device__ __forceinline__ void pair_idx(
    int p, const int* __restrict__ pu, const int* __restrict__ pv,
    const int* __restrict__ nu, const int* __restrict__ nv, int& iu, int& iv)
{
    if (p < Bn) { iu = pu[p];      iv = pv[p]; }
    else        { iu = nu[p - Bn]; iv = nv[p - Bn]; }
}

__device__ __forceinline__ float softplus_neg(float s) {
    // -log_sigmoid(s) = softplus(-s), stable
    float y = -s;
    return fmaxf(y, 0.f) + log1pf(expf(-fabsf(y)));
}

__device__ __forceinline__ float red16(float s) {
    s += __shfl_xor(s, 1);
    s += __shfl_xor(s, 2);
    s += __shfl_xor(s, 4);
    s += __shfl_xor(s, 8);
    return s;
}

__global__ __launch_bounds__(BDIM) void w2v_partial(
    const int* __restrict__ pos_u, const int* __restrict__ pos_v,
    const int* __restrict__ neg_u, const int* __restrict__ neg_v,
    const float* __restrict__ u_emb, const float* __restrict__ v_emb,
    float* __restrict__ out)
{
    const int lane16 = threadIdx.x & 15;
    const int group  = (blockIdx.x * BDIM + threadIdx.x) >> 4;
    const int doff   = lane16 << 2;

    float acc = 0.f;
    int p = group;
    // unroll-by-2: 4 outstanding float4 row-loads per group (best measured config)
    for (; p + NGROUPS < NPAIRS; p += 2 * NGROUPS) {
        int iu0, iv0, iu1, iv1;
        pair_idx(p,           pos_u, pos_v, neg_u, neg_v, iu0, iv0);
        pair_idx(p + NGROUPS, pos_u, pos_v, neg_u, neg_v, iu1, iv1);

        const float4 a0 = *reinterpret_cast<const float4*>(u_emb + (size_t)iu0 * Dn + doff);
        const float4 b0 = *reinterpret_cast<const float4*>(v_emb + (size_t)iv0 * Dn + doff);
        const float4 a1 = *reinterpret_cast<const float4*>(u_emb + (size_t)iu1 * Dn + doff);
        const float4 b1 = *reinterpret_cast<const float4*>(v_emb + (size_t)iv1 * Dn + doff);

        float s0 = a0.x*b0.x + a0.y*b0.y + a0.z*b0.z + a0.w*b0.w;
        float s1 = a1.x*b1.x + a1.y*b1.y + a1.z*b1.z + a1.w*b1.w;
        s0 = red16(s0);
        s1 = red16(s1);
        if (lane16 == 0) acc += softplus_neg(s0) + softplus_neg(s1);
    }
    if (p < NPAIRS) {
        int iu, iv;
        pair_idx(p, pos_u, pos_v, neg_u, neg_v, iu, iv);
        const float4 a = *reinterpret_cast<const float4*>(u_emb + (size_t)iu * Dn + doff);
        const float4 b = *reinterpret_cast<const float4*>(v_emb + (size_t)iv * Dn + doff);
        float s = a.x*b.x + a.y*b.y + a.z*b.z + a.w*b.w;
        s = red16(s);
        if (lane16 == 0) acc += softplus_neg(s);
    }

    // block reduction: acc lives at lanes 0 mod 16
    acc += __shfl_xor(acc, 16);
    acc += __shfl_xor(acc, 32);
    __shared__ float red[BDIM / 64];
    if ((threadIdx.x & 63) == 0) red[threadIdx.x >> 6] = acc;
    __syncthreads();
    if (threadIdx.x == 0) {
        float bsum = red[0] + red[1] + red[2] + red[3];
        atomicAdd(out, bsum);   // result unused -> fire-and-forget, device scope
    }
}

extern "C" void kernel_launch(void* const* d_in, const int* in_sizes, int n_in,
                              void* d_out, int out_size, void* d_ws, size_t ws_size,
                              hipStream_t stream) {
    const int*   pos_u = (const int*)d_in[0];
    const int*   pos_v = (const int*)d_in[1];
    const int*   neg_u = (const int*)d_in[2];
    const int*   neg_v = (const int*)d_in[3];
    const float* u_emb = (const float*)d_in[4];
    const float* v_emb = (const float*)d_in[5];
    float* out = (float*)d_out;

    // zero the accumulator every call (graph replays don't re-poison d_out)
    hipMemsetAsync(out, 0, sizeof(float), stream);

    w2v_partial<<<NBLOCKS, BDIM, 0, stream>>>(pos_u, pos_v, neg_u, neg_v,
                                              u_emb, v_emb, out);
}

// Round 5
// 36.909 us; speedup vs baseline: 1.5043x; 1.5043x over previous
//
#include <hip/hip_runtime.h>

// Word2vec SGNS loss: sum over B*(K+1)=344064 pairs of softplus(-dot64(u_row,v_row)).
// fp32 embeddings, 1e6 x 64 (256 B rows, 16B-aligned). ~176 MB logical gather;
// ~88 MB from HBM (L3 retains half across replays) at ~2.9 TB/s random-256B
// efficiency => kernel1 ~30 us is the HBM-random floor. MLP saturated (unroll-1
// == unroll-4 within noise). Epilogue lessons (measured): 2048 same-address
// device atomics cost ~21 cy each (+18 us); ACQ_REL RMWs ~60 ns each (+117 us).
// A separate 1-block reduce kernel (~5 us incl. launch) is the cheapest tail.

constexpr int Bn = 16384;
constexpr int Kn = 20;
constexpr int Dn = 64;
constexpr int NPAIRS = Bn * (Kn + 1);   // 344064

#define BDIM 256
#define NBLOCKS 2048

__global__ __launch_bounds__(BDIM) void w2v_partial(
    const int* __restrict__ pos_u, const int* __restrict__ pos_v,
    const int* __restrict__ neg_u, const int* __restrict__ neg_v,
    const float* __restrict__ u_emb, const float* __restrict__ v_emb,
    float* __restrict__ partials)
{
    const int lane16 = threadIdx.x & 15;
    const int group  = (blockIdx.x * BDIM + threadIdx.x) >> 4;   // global 16-lane group
    const int ngroups = (NBLOCKS * BDIM) >> 4;                   // 32768

    float acc = 0.f;
    for (int p = group; p < NPAIRS; p += ngroups) {
        int iu, iv;
        if (p < Bn) { iu = pos_u[p];      iv = pos_v[p]; }
        else        { iu = neg_u[p - Bn]; iv = neg_v[p - Bn]; }  // neg_[uv] flat [B*K]

        const float4 a = *reinterpret_cast<const float4*>(u_emb + (size_t)iu * Dn + (lane16 << 2));
        const float4 b = *reinterpret_cast<const float4*>(v_emb + (size_t)iv * Dn + (lane16 << 2));
        float s = a.x*b.x + a.y*b.y + a.z*b.z + a.w*b.w;

        // reduce dot across the 16 lanes of this group
        s += __shfl_xor(s, 1);
        s += __shfl_xor(s, 2);
        s += __shfl_xor(s, 4);
        s += __shfl_xor(s, 8);

        if (lane16 == 0) {
            // -log_sigmoid(s) = softplus(-s), numerically stable form
            float y = -s;
            acc += fmaxf(y, 0.f) + log1pf(expf(-fabsf(y)));
        }
    }

    // wave reduce: acc nonzero at lanes 0,16,32,48
    acc += __shfl_xor(acc, 16);
    acc += __shfl_xor(acc, 32);

    __shared__ float red[BDIM / 64];
    if ((threadIdx.x & 63) == 0) red[threadIdx.x >> 6] = acc;
    __syncthreads();
    if (threadIdx.x == 0)
        partials[blockIdx.x] = red[0] + red[1] + red[2] + red[3];
}

__global__ __launch_bounds__(BDIM) void w2v_reduce(
    const float* __restrict__ partials, float* __restrict__ out)
{
    float s = 0.f;
    for (int i = threadIdx.x; i < NBLOCKS; i += BDIM) s += partials[i];
    s += __shfl_xor(s, 1);
    s += __shfl_xor(s, 2);
    s += __shfl_xor(s, 4);
    s += __shfl_xor(s, 8);
    s += __shfl_xor(s, 16);
    s += __shfl_xor(s, 32);
    __shared__ float red[BDIM / 64];
    if ((threadIdx.x & 63) == 0) red[threadIdx.x >> 6] = s;
    __syncthreads();
    if (threadIdx.x == 0) out[0] = red[0] + red[1] + red[2] + red[3];
}

extern "C" void kernel_launch(void* const* d_in, const int* in_sizes, int n_in,
                              void* d_out, int out_size, void* d_ws, size_t ws_size,
                              hipStream_t stream) {
    const int*   pos_u = (const int*)d_in[0];
    const int*   pos_v = (const int*)d_in[1];
    const int*   neg_u = (const int*)d_in[2];
    const int*   neg_v = (const int*)d_in[3];
    const float* u_emb = (const float*)d_in[4];
    const float* v_emb = (const float*)d_in[5];
    float* out = (float*)d_out;
    float* partials = (float*)d_ws;   // NBLOCKS floats = 8 KB

    w2v_partial<<<NBLOCKS, BDIM, 0, stream>>>(pos_u, pos_v, neg_u, neg_v,
                                              u_emb, v_emb, partials);
    w2v_reduce<<<1, BDIM, 0, stream>>>(partials, out);
}

// Round 6
// 36.390 us; speedup vs baseline: 1.5258x; 1.0143x over previous
//
#include <hip/hip_runtime.h>

// Word2vec SGNS loss: sum over B*(K+1)=344064 pairs of softplus(-dot64(u_row,v_row)).
// fp32 embeddings, 1e6 x 64 (256 B rows, 16B-aligned). ~176 MB logical gather;
// ~88 MB from HBM (L3 serves rest) at ~2.9 TB/s random-256B fetch rate =>
// kernel1 ~30 us is the HBM-random floor. MLP saturated (unroll-1 == unroll-4).
// Epilogue lessons (measured): same-address device atomics +18us (relaxed,
// no-return) / +117us (ACQ_REL w/ return) — a 1-block reduce kernel is cheapest.
// This round: 4096 blocks (2 scheduling passes/CU -> smoother drain) + float4
// partials read in kernel2.

constexpr int Bn = 16384;
constexpr int Kn = 20;
constexpr int Dn = 64;
constexpr int NPAIRS = Bn * (Kn + 1);   // 344064

#define BDIM 256
#define NBLOCKS 4096
#define NGROUPS ((NBLOCKS * BDIM) >> 4)   // 65536 16-lane groups

__global__ __launch_bounds__(BDIM) void w2v_partial(
    const int* __restrict__ pos_u, const int* __restrict__ pos_v,
    const int* __restrict__ neg_u, const int* __restrict__ neg_v,
    const float* __restrict__ u_emb, const float* __restrict__ v_emb,
    float* __restrict__ partials)
{
    const int lane16 = threadIdx.x & 15;
    const int group  = (blockIdx.x * BDIM + threadIdx.x) >> 4;   // global 16-lane group

    float acc = 0.f;
    for (int p = group; p < NPAIRS; p += NGROUPS) {
        int iu, iv;
        if (p < Bn) { iu = pos_u[p];      iv = pos_v[p]; }
        else        { iu = neg_u[p - Bn]; iv = neg_v[p - Bn]; }  // neg_[uv] flat [B*K]

        const float4 a = *reinterpret_cast<const float4*>(u_emb + (size_t)iu * Dn + (lane16 << 2));
        const float4 b = *reinterpret_cast<const float4*>(v_emb + (size_t)iv * Dn + (lane16 << 2));
        float s = a.x*b.x + a.y*b.y + a.z*b.z + a.w*b.w;

        // reduce dot across the 16 lanes of this group
        s += __shfl_xor(s, 1);
        s += __shfl_xor(s, 2);
        s += __shfl_xor(s, 4);
        s += __shfl_xor(s, 8);

        if (lane16 == 0) {
            // -log_sigmoid(s) = softplus(-s), numerically stable form
            float y = -s;
            acc += fmaxf(y, 0.f) + log1pf(expf(-fabsf(y)));
        }
    }

    // wave reduce: acc nonzero at lanes 0,16,32,48
    acc += __shfl_xor(acc, 16);
    acc += __shfl_xor(acc, 32);

    __shared__ float red[BDIM / 64];
    if ((threadIdx.x & 63) == 0) red[threadIdx.x >> 6] = acc;
    __syncthreads();
    if (threadIdx.x == 0)
        partials[blockIdx.x] = red[0] + red[1] + red[2] + red[3];
}

__global__ __launch_bounds__(BDIM) void w2v_reduce(
    const float* __restrict__ partials, float* __restrict__ out)
{
    // NBLOCKS floats read as float4: NBLOCKS/4 = 1024 vec4 / 256 threads = 4 iters
    float s = 0.f;
    const float4* p4 = reinterpret_cast<const float4*>(partials);
    for (int i = threadIdx.x; i < NBLOCKS / 4; i += BDIM) {
        float4 v = p4[i];
        s += (v.x + v.y) + (v.z + v.w);
    }
    s += __shfl_xor(s, 1);
    s += __shfl_xor(s, 2);
    s += __shfl_xor(s, 4);
    s += __shfl_xor(s, 8);
    s += __shfl_xor(s, 16);
    s += __shfl_xor(s, 32);
    __shared__ float red[BDIM / 64];
    if ((threadIdx.x & 63) == 0) red[threadIdx.x >> 6] = s;
    __syncthreads();
    if (threadIdx.x == 0) out[0] = red[0] + red[1] + red[2] + red[3];
}

extern "C" void kernel_launch(void* const* d_in, const int* in_sizes, int n_in,
                              void* d_out, int out_size, void* d_ws, size_t ws_size,
                              hipStream_t stream) {
    const int*   pos_u = (const int*)d_in[0];
    const int*   pos_v = (const int*)d_in[1];
    const int*   neg_u = (const int*)d_in[2];
    const int*   neg_v = (const int*)d_in[3];
    const float* u_emb = (const float*)d_in[4];
    const float* v_emb = (const float*)d_in[5];
    float* out = (float*)d_out;
    float* partials = (float*)d_ws;   // NBLOCKS floats = 16 KB

    w2v_partial<<<NBLOCKS, BDIM, 0, stream>>>(pos_u, pos_v, neg_u, neg_v,
                                              u_emb, v_emb, partials);
    w2v_reduce<<<1, BDIM, 0, stream>>>(partials, out);
}